// Round 2
// baseline (35764.487 us; speedup 1.0000x reference)
//
#include <hip/hip_runtime.h>
#include <math.h>

#define BB 32
#define SSS 1024
#define EE 256
#define HHH 256
#define TEAM 8
#define CHUNK 128   // SSS / TEAM
#define NTHR 512

#define NEG_INF (-__builtin_huge_valf())

__device__ __forceinline__ float sigm_precise(float x) {
  return 1.0f / (1.0f + expf(-x));
}

// Monotonic-counter team barrier (8 blocks). Release/acquire atomics make the
// compiler emit the correct agent-scope L2 writeback/invalidate on gfx950.
__device__ __forceinline__ void team_bar(int* cnt, int target) {
  __syncthreads();
  if (threadIdx.x == 0) {
    __hip_atomic_fetch_add(cnt, 1, __ATOMIC_RELEASE, __HIP_MEMORY_SCOPE_AGENT);
    while (__hip_atomic_load(cnt, __ATOMIC_ACQUIRE, __HIP_MEMORY_SCOPE_AGENT) < target) {}
  }
  __syncthreads();
}

__global__ __launch_bounds__(NTHR) void ptrnet(
    const float* __restrict__ enc, const float* __restrict__ dec0,
    const float* __restrict__ h0, const float* __restrict__ c0,
    const float* __restrict__ context,
    const float* __restrict__ W_ih, const float* __restrict__ b_ih,
    const float* __restrict__ W_hh, const float* __restrict__ b_hh,
    const float* __restrict__ W_out, const float* __restrict__ b_out,
    const float* __restrict__ Wa_in, const float* __restrict__ ba_in,
    const float* __restrict__ Wa_ctx, const float* __restrict__ ba_ctx,
    const float* __restrict__ v,
    float* __restrict__ out,
    int* __restrict__ barp,
    float* __restrict__ hbuf, float* __restrict__ htbuf,
    float* __restrict__ pinp, float* __restrict__ stats,
    float* __restrict__ accb)
{
  // ---- LDS (~147 KB total) ----
  __shared__ __align__(16) float cp[CHUNK * HHH];   // ctx_proj chunk [slot][h]
  __shared__ __align__(16) float inp_s[HHH];
  __shared__ __align__(16) float v_s[HHH];
  __shared__ float attn_s[HHH];
  __shared__ float ht_s[HHH];
  __shared__ float hx_s[HHH];                        // carry h (h_out prev)
  __shared__ float x_s[EE];
  __shared__ float gates_s[128];
  __shared__ float scratch[512];
  __shared__ __align__(16) float acc_s[TEAM][HHH];
  __shared__ float wst[TEAM][4];                     // per-wave m,l,bestv,bestidx
  __shared__ float score_s[CHUNK];
  __shared__ float bg_s[128];
  __shared__ float bain_s[HHH];
  __shared__ float bo_s[32];
  __shared__ float htl_s[32];                        // local h_t slice
  __shared__ float c_s[32];                          // cell-state slice
  __shared__ float scale8_s[TEAM];
  __shared__ float mg_sh, lg_sh;
  __shared__ int idx_sh, n_sh;
  __shared__ unsigned short list_s[CHUNK];

  const int tid = threadIdx.x;
  const int b = blockIdx.x & 31;   // batch
  const int m = blockIdx.x >> 5;   // team member 0..7 (same XCD under %8 RR)
  int* cnt = barp + b * 32;        // 128B-strided counters

  // ================= one-time: ctx_proj chunk into LDS (fp64 accumulate) ====
  const float* ctxp = context + ((size_t)b * SSS + (size_t)m * CHUNK) * HHH;
  for (int i = tid; i < CHUNK * HHH; i += NTHR) cp[i] = ctxp[i];
  __syncthreads();
  {
    const int cc = tid & 255;
    const int rgc = tid >> 8;  // rows rgc*64+k
    double acc[64];
    double bc = (double)ba_ctx[cc];
#pragma unroll
    for (int k = 0; k < 64; ++k) acc[k] = 0.0;
    for (int h = 0; h < HHH; ++h) {
      double w = (double)Wa_ctx[h * HHH + cc];
      const float* base = &cp[(rgc * 64) * HHH + h];
#pragma unroll
      for (int k = 0; k < 64; ++k) acc[k] = fma((double)base[k * HHH], w, acc[k]);
    }
    __syncthreads();  // all reads of raw context done
#pragma unroll
    for (int k = 0; k < 64; ++k) cp[(rgc * 64 + k) * HHH + cc] = (float)(acc[k] + bc);
  }

  // ================= persistent weight registers =================
  const int q = tid & 127, rg = tid >> 7;                 // gates: col q, row-chunk rg
  const int gcol = ((q >> 5) * 256) + m * 32 + (q & 31);  // global gate column
  float w_ih_r[64], w_hh_r[64];
#pragma unroll
  for (int k = 0; k < 64; ++k) {
    w_ih_r[k] = W_ih[(size_t)(rg * 64 + k) * 1024 + gcol];
    w_hh_r[k] = W_hh[(size_t)(rg * 64 + k) * 1024 + gcol];
  }
  const int hp = tid & 255, rh = tid >> 8;                // pinp: col hp, row-half rh
  float w_ain_r[16];
#pragma unroll
  for (int k = 0; k < 16; ++k)
    w_ain_r[k] = Wa_in[(size_t)(m * 32 + rh * 16 + k) * HHH + hp];
  const int c2 = tid & 31, rgo = tid >> 5;                // h_out: col c2, row-chunk rgo
  float w_out_r[32];
#pragma unroll
  for (int k = 0; k < 32; ++k)
    w_out_r[k] = W_out[(size_t)(rgo * 32 + k) * HHH + m * 32 + c2];

  // ================= LDS init =================
  if (tid < 128) {
    int j = ((tid >> 5) * 256) + m * 32 + (tid & 31);
    bg_s[tid] = b_ih[j] + b_hh[j];
    list_s[tid] = (unsigned short)tid;
  }
  if (tid < 256) { bain_s[tid] = ba_in[tid]; v_s[tid] = v[tid]; }
  if (tid < 32)  { bo_s[tid] = b_out[m * 32 + tid]; c_s[tid] = c0[b * HHH + m * 32 + tid]; }
  if (tid == 0)  { n_sh = CHUNK; }
  __syncthreads();

  int bart = 0;
  const int lane = tid & 63, wv = tid >> 6;

  for (int t = 0; t < SSS; ++t) {
    // ------- A: gates -> LSTM -> h_t slice -> pinp partial -------
    if (tid < 256) {
      if (t == 0) { x_s[tid] = dec0[b * EE + tid]; hx_s[tid] = h0[b * HHH + tid]; }
      else {
        int ix = idx_sh;
        x_s[tid] = enc[((size_t)b * SSS + ix) * EE + tid];
        hx_s[tid] = hbuf[b * HHH + tid];
      }
    }
    __syncthreads();
    {
      float g = 0.0f;
      const float* xb = &x_s[rg * 64];
      const float* hb = &hx_s[rg * 64];
#pragma unroll
      for (int k = 0; k < 64; ++k) g = fmaf(w_ih_r[k], xb[k], g);
#pragma unroll
      for (int k = 0; k < 64; ++k) g = fmaf(w_hh_r[k], hb[k], g);
      scratch[rg * 128 + q] = g;
    }
    __syncthreads();
    if (tid < 128)
      gates_s[tid] = scratch[tid] + scratch[128 + tid] + scratch[256 + tid] + scratch[384 + tid] + bg_s[tid];
    __syncthreads();
    if (tid < 32) {
      float gi = gates_s[tid], gf = gates_s[32 + tid], gg = gates_s[64 + tid], go = gates_s[96 + tid];
      float cn = sigm_precise(gf) * c_s[tid] + sigm_precise(gi) * tanhf(gg);
      float ht = sigm_precise(go) * tanhf(cn);
      c_s[tid] = cn; htl_s[tid] = ht;
      htbuf[b * HHH + m * 32 + tid] = ht;
    }
    __syncthreads();
    {
      float p = 0.0f;
#pragma unroll
      for (int k = 0; k < 16; ++k) p = fmaf(w_ain_r[k], htl_s[rh * 16 + k], p);
      scratch[rh * 256 + hp] = p;
    }
    __syncthreads();
    if (tid < 256) pinp[((b * TEAM) + m) * HHH + tid] = scratch[tid] + scratch[256 + tid];
    bart += TEAM; team_bar(cnt, bart);

    // ------- B: scores (accurate) + online softmax + acc over live chunk -------
    if (tid < 128) score_s[tid] = NEG_INF;
    if (tid < 256) {
      float s = bain_s[tid];
#pragma unroll
      for (int w = 0; w < TEAM; ++w) s += pinp[((b * TEAM) + w) * HHH + tid];
      inp_s[tid] = s;
    }
    __syncthreads();
    {
      float4 inp4 = *reinterpret_cast<const float4*>(&inp_s[lane * 4]);
      float4 v4   = *reinterpret_cast<const float4*>(&v_s[lane * 4]);
      float mw = NEG_INF, lw = 0.0f, a0 = 0, a1 = 0, a2 = 0, a3 = 0;
      float bvv = NEG_INF; int bii = 0x7fffffff;
      int n = n_sh;
      for (int k = wv; k < n; k += TEAM) {
        int slot = list_s[k];
        float4 c4 = *reinterpret_cast<const float4*>(&cp[slot * HHH + lane * 4]);
        // precise tanh + fp64 dot: score error ~1e-8 vs fp64 reference
        float t0 = tanhf(inp4.x + c4.x), t1 = tanhf(inp4.y + c4.y);
        float t2 = tanhf(inp4.z + c4.z), t3 = tanhf(inp4.w + c4.w);
        double p = fma((double)v4.x, (double)t0,
                   fma((double)v4.y, (double)t1,
                   fma((double)v4.z, (double)t2,
                       (double)v4.w * (double)t3)));
#pragma unroll
        for (int d = 1; d < 64; d <<= 1) p += __shfl_xor(p, d);
        float sc = (float)p;  // lane-uniform
        int sg = m * CHUNK + slot;
        bool bet = (sc > bvv) || (sc == bvv && sg < bii);
        bvv = bet ? sc : bvv; bii = bet ? sg : bii;
        float nm = fmaxf(mw, sc);
        float scl = __expf(mw - nm);   // first iter: exp(-inf)=0, no NaN
        float ws  = __expf(sc - nm);
        lw = lw * scl + ws;
        a0 = fmaf(ws, c4.x, a0 * scl); a1 = fmaf(ws, c4.y, a1 * scl);
        a2 = fmaf(ws, c4.z, a2 * scl); a3 = fmaf(ws, c4.w, a3 * scl);
        mw = nm;
        if (lane == 0) score_s[slot] = sc;
      }
      *reinterpret_cast<float4*>(&acc_s[wv][lane * 4]) = make_float4(a0, a1, a2, a3);
      if (lane == 0) { wst[wv][0] = mw; wst[wv][1] = lw; wst[wv][2] = bvv; wst[wv][3] = __int_as_float(bii); }
    }
    __syncthreads();
    if (tid == 0) {
      float mc = NEG_INF;
#pragma unroll
      for (int w = 0; w < TEAM; ++w) if (wst[w][1] > 0.0f) mc = fmaxf(mc, wst[w][0]);
      float lc = 0.0f, bvv = NEG_INF; int bii = 0x7fffffff;
#pragma unroll
      for (int w = 0; w < TEAM; ++w) {
        float sw = (wst[w][1] > 0.0f) ? __expf(wst[w][0] - mc) : 0.0f;
        scale8_s[w] = sw;
        lc += wst[w][1] * sw;
        float wb = wst[w][2]; int wi = __float_as_int(wst[w][3]);
        bool bet = (wb > bvv) || (wb == bvv && wi < bii);
        bvv = bet ? wb : bvv; bii = bet ? wi : bii;
      }
      float* st = &stats[((b * TEAM) + m) * 4];
      st[0] = mc; st[1] = lc; st[2] = bvv; st[3] = __int_as_float(bii);
    }
    __syncthreads();
    if (tid < 256) {
      float a = 0.0f;
#pragma unroll
      for (int w = 0; w < TEAM; ++w) a += acc_s[w][tid] * scale8_s[w];
      accb[((b * TEAM) + m) * HHH + tid] = a;
    }
    bart += TEAM; team_bar(cnt, bart);

    // ------- C: global combine -> h_out slice -> outputs -> mask -------
    if (tid == 0) {
      float mcv[TEAM], lcv[TEAM];
      float mg = NEG_INF;
#pragma unroll
      for (int w = 0; w < TEAM; ++w) {
        const float* st = &stats[((b * TEAM) + w) * 4];
        mcv[w] = st[0]; lcv[w] = st[1];
        if (lcv[w] > 0.0f) mg = fmaxf(mg, mcv[w]);
      }
      float lg = 0.0f, bvv = NEG_INF; int bii = 0x7fffffff;
#pragma unroll
      for (int w = 0; w < TEAM; ++w) {
        float sw = (lcv[w] > 0.0f) ? __expf(mcv[w] - mg) : 0.0f;
        scale8_s[w] = sw; lg += lcv[w] * sw;
        const float* st = &stats[((b * TEAM) + w) * 4];
        float wb = st[2]; int wi = __float_as_int(st[3]);
        bool bet = (wb > bvv) || (wb == bvv && wi < bii);
        bvv = bet ? wb : bvv; bii = bet ? wi : bii;
      }
      mg_sh = mg; lg_sh = lg; idx_sh = bii;
    }
    __syncthreads();
    if (tid < 256) {
      float a = 0.0f;
#pragma unroll
      for (int w = 0; w < TEAM; ++w) a += accb[((b * TEAM) + w) * HHH + tid] * scale8_s[w];
      attn_s[tid] = a / lg_sh;
      ht_s[tid] = htbuf[b * HHH + tid];
    }
    __syncthreads();
    {
      float hpart = 0.0f;
#pragma unroll
      for (int k = 0; k < 32; ++k) {
        int r = rgo * 32 + k;
        float vr = (r < 256) ? attn_s[r] : ht_s[r - 256];
        hpart = fmaf(w_out_r[k], vr, hpart);
      }
      scratch[rgo * 32 + c2] = hpart;
    }
    __syncthreads();
    if (tid < 32) {
      float s = bo_s[tid];
#pragma unroll
      for (int j = 0; j < 16; ++j) s += scratch[j * 32 + tid];
      hbuf[b * HHH + m * 32 + tid] = tanhf(s);
    }
    if (tid < 128) {
      float sc = score_s[tid];
      float al = (sc <= NEG_INF) ? 0.0f : expf(sc - mg_sh) / lg_sh;
      out[(size_t)b * (SSS * SSS) + (size_t)t * SSS + m * CHUNK + tid] = al;
    }
    if (m == 0 && tid == 0)
      out[(size_t)BB * SSS * SSS + (size_t)b * SSS + t] = (float)idx_sh;
    if (tid == 0) {
      int ix = idx_sh;
      if ((ix >> 7) == m) {   // selected position in my chunk: drop from live list
        int slot = ix & 127;
        int n = n_sh, pos = -1;
        for (int k2 = 0; k2 < n; ++k2) if (list_s[k2] == (unsigned short)slot) { pos = k2; break; }
        if (pos >= 0) { list_s[pos] = list_s[n - 1]; n_sh = n - 1; }
      }
    }
    bart += TEAM; team_bar(cnt, bart);
  }
}

extern "C" void kernel_launch(void* const* d_in, const int* in_sizes, int n_in,
                              void* d_out, int out_size, void* d_ws, size_t ws_size,
                              hipStream_t stream) {
  (void)in_sizes; (void)n_in; (void)out_size; (void)ws_size;
  const float* enc     = (const float*)d_in[0];
  const float* dec0    = (const float*)d_in[1];
  const float* h0      = (const float*)d_in[2];
  const float* c0      = (const float*)d_in[3];
  const float* context = (const float*)d_in[4];
  const float* W_ih    = (const float*)d_in[5];
  const float* b_ih    = (const float*)d_in[6];
  const float* W_hh    = (const float*)d_in[7];
  const float* b_hh    = (const float*)d_in[8];
  const float* W_out   = (const float*)d_in[9];
  const float* b_out   = (const float*)d_in[10];
  const float* Wa_in   = (const float*)d_in[11];
  const float* ba_in   = (const float*)d_in[12];
  const float* Wa_ctx  = (const float*)d_in[13];
  const float* ba_ctx  = (const float*)d_in[14];
  const float* v       = (const float*)d_in[15];

  char* wsb   = (char*)d_ws;
  int*  barp  = (int*)wsb;                          // 32 teams * 32 ints = 4 KB
  float* hbuf  = (float*)(wsb + 4096);              // [32][256]
  float* htbuf = hbuf + 32 * 256;                   // [32][256]
  float* pinp  = htbuf + 32 * 256;                  // [32][8][256]
  float* stats = pinp + 32 * 8 * 256;               // [32][8][4]
  float* accb  = stats + 32 * 8 * 4;                // [32][8][256]

  hipMemsetAsync(d_ws, 0, 4096, stream);            // reset barrier counters
  hipLaunchKernelGGL(ptrnet, dim3(256), dim3(NTHR), 0, stream,
                     enc, dec0, h0, c0, context,
                     W_ih, b_ih, W_hh, b_hh, W_out, b_out,
                     Wa_in, ba_in, Wa_ctx, ba_ctx, v,
                     (float*)d_out, barp, hbuf, htbuf, pinp, stats, accb);
}